// Round 10
// baseline (274.886 us; speedup 1.0000x reference)
//
#include <hip/hip_runtime.h>
#include <hip/hip_bf16.h>

#define L_SEQ 2048
#define HIDN  1024
#define NH    16
#define DHD   64
#define QKV_P 3200   // padded GEMM N: 3072 qkv + 16 dt rows + 112 pad
#define QC_S  2048   // qc stride: Q(1024) + K(1024); V goes to vt

typedef float f4 __attribute__((ext_vector_type(4)));
typedef __bf16 bf16x8 __attribute__((ext_vector_type(8)));
typedef _Float16 half8 __attribute__((ext_vector_type(8)));
typedef unsigned int u32x2 __attribute__((ext_vector_type(2)));

union H8 {
  half8 h;
  u32x2 u2[2];
  uint4 u4;
};

__device__ __forceinline__ float b2f(unsigned short u) {
  union { unsigned int i; float f; } c; c.i = ((unsigned int)u) << 16; return c.f;
}
__device__ __forceinline__ unsigned short f2b(float f) {
  union { float f; unsigned int i; } c; c.f = f;
  unsigned int r = c.i + 0x7FFFu + ((c.i >> 16) & 1u);
  return (unsigned short)(r >> 16);
}
__device__ __forceinline__ unsigned short f2h(float f) {
  union { _Float16 h; unsigned short u; } c; c.h = (_Float16)f; return c.u;
}

// ------------- fused prep: dtype detect + canonicalize all params ----------
// qkvw_b is [3200][1024] bf16: rows 0-3071 = qkv_w, 3072-3087 = dt_proj_w,
// 3088-3199 = zeros. smallf layout: qw@0(2048) qb@2048(1024) kw@3072(2048)
// kb@5120(1024) vw@6144(2048) vb@8192(1024) nw@9216(64) al@9280(16)
// dt_bias@9296(16) dt_proj_b@9312(16) oc@9328(16)  total 9344
__global__ __launch_bounds__(256) void prep_kernel(
    const void* hs, const void* qkvw, const void* ow, const void* dtw,
    const void* qw, const void* qb, const void* kw, const void* kb,
    const void* vw, const void* vb, const void* nw, const void* al,
    const void* dtb, const void* dpb, const void* oc,
    unsigned short* __restrict__ hs_b, unsigned short* __restrict__ qkvw_b,
    unsigned short* __restrict__ ow_b,
    float* __restrict__ smallf, int* __restrict__ flag)
{
  __shared__ int cnt;
  if (threadIdx.x == 0) cnt = 0;
  __syncthreads();
  {
    const unsigned short* p = (const unsigned short*)hs;
    int c = 0;
    for (int i = threadIdx.x; i < 8192; i += 256)
      if (((p[i] >> 7) & 0xFFu) >= 140u) c++;
    atomicAdd(&cnt, c);
  }
  __syncthreads();
  const int f = (cnt >= 32) ? 1 : 0;          // 1 = fp32 inputs
  if (blockIdx.x == 0 && threadIdx.x == 0) *flag = f;

  const int tid = blockIdx.x * 256 + threadIdx.x;
  const int nth = gridDim.x * 256;
  // 4-elem groups: hs 524288 | qkvw 786432 | dtw 4096 | pad 28672 | ow 262144
  for (int i = tid; i < 1605632; i += nth) {
    const void* src; unsigned short* dst; int off;
    if (i < 524288)       { src = hs;   dst = hs_b;   off = i; }
    else if (i < 1310720) { src = qkvw; dst = qkvw_b; off = i - 524288; }
    else if (i < 1314816) { src = dtw;  dst = qkvw_b + 3072 * 1024; off = i - 1310720; }
    else if (i < 1343488) {  // zero pad rows 3088-3199
      *(ushort4*)(qkvw_b + 3088 * 1024 + (i - 1314816) * 4) = (ushort4){0, 0, 0, 0};
      continue;
    }
    else                  { src = ow;   dst = ow_b;   off = i - 1343488; }
    const int e = off * 4;
    if (f) {
      f4 v = *(const f4*)((const float*)src + e);
      ushort4 o;
      o.x = f2b(v[0]); o.y = f2b(v[1]); o.z = f2b(v[2]); o.w = f2b(v[3]);
      *(ushort4*)(dst + e) = o;
    } else {
      *(uint2*)(dst + e) = *(const uint2*)((const unsigned short*)src + e);
    }
  }
  const void* ptrs[11] = {qw, qb, kw, kb, vw, vb, nw, al, dtb, dpb, oc};
  const int sizes[11] = {2048, 1024, 2048, 1024, 2048, 1024, 64, 16, 16, 16, 16};
  int off = 0;
  for (int a = 0; a < 11; ++a) {
    for (int i = tid; i < sizes[a]; i += nth)
      smallf[off + i] = f ? ((const float*)ptrs[a])[i]
                          : b2f(((const unsigned short*)ptrs[a])[i]);
    off += sizes[a];
  }
}

// ------- C = A (MxK) * B^T (NxK), bf16 in, fp32 out, 128x128 tile ---------
__global__ __launch_bounds__(256) void gemm128(
    const unsigned short* __restrict__ A, const unsigned short* __restrict__ B,
    float* __restrict__ C, int M, int N, int K)
{
  __shared__ __align__(16) unsigned short As[128 * 40];
  __shared__ __align__(16) unsigned short Bs[128 * 40];
  const int t = threadIdx.x;
  const int w = t >> 6, lane = t & 63;
  const int quad = lane >> 4, l16 = lane & 15;
  const int wr = w >> 1, wc = w & 1;
  const int m0 = blockIdx.y * 128, n0 = blockIdx.x * 128;
  const int srow = t >> 1;
  const int scol = (t & 1) * 16;

  f4 acc[4][4];
#pragma unroll
  for (int i = 0; i < 4; ++i)
#pragma unroll
    for (int j = 0; j < 4; ++j) acc[i][j] = (f4){0.f, 0.f, 0.f, 0.f};

  const unsigned short* apg = A + (size_t)(m0 + srow) * K + scol;
  const unsigned short* bpg = B + (size_t)(n0 + srow) * K + scol;
  uint4 a0 = *(const uint4*)apg,       a1 = *(const uint4*)(apg + 8);
  uint4 b0 = *(const uint4*)bpg,       b1 = *(const uint4*)(bpg + 8);

  for (int k0 = 0; k0 < K; k0 += 32) {
    __syncthreads();
    *(uint4*)&As[srow * 40 + scol]     = a0;
    *(uint4*)&As[srow * 40 + scol + 8] = a1;
    *(uint4*)&Bs[srow * 40 + scol]     = b0;
    *(uint4*)&Bs[srow * 40 + scol + 8] = b1;
    __syncthreads();
    if (k0 + 32 < K) {
      a0 = *(const uint4*)(apg + k0 + 32); a1 = *(const uint4*)(apg + k0 + 40);
      b0 = *(const uint4*)(bpg + k0 + 32); b1 = *(const uint4*)(bpg + k0 + 40);
    }
    bf16x8 aF[4], bF[4];
#pragma unroll
    for (int i = 0; i < 4; ++i)
      aF[i] = *(const bf16x8*)&As[(wr * 64 + i * 16 + l16) * 40 + quad * 8];
#pragma unroll
    for (int j = 0; j < 4; ++j)
      bF[j] = *(const bf16x8*)&Bs[(wc * 64 + j * 16 + l16) * 40 + quad * 8];
#pragma unroll
    for (int i = 0; i < 4; ++i)
#pragma unroll
      for (int j = 0; j < 4; ++j)
        acc[i][j] = __builtin_amdgcn_mfma_f32_16x16x32_bf16(aF[i], bF[j], acc[i][j], 0, 0, 0);
  }

#pragma unroll
  for (int i = 0; i < 4; ++i)
#pragma unroll
    for (int j = 0; j < 4; ++j)
#pragma unroll
      for (int r = 0; r < 4; ++r) {
        int m = m0 + wr * 64 + i * 16 + quad * 4 + r;
        int n = n0 + wc * 64 + j * 16 + l16;
        C[(size_t)m * N + n] = acc[i][j][r];
      }
}

// ---------------- C = A (MxK) * B^T (NxK), bf16 in, 64x64 tile --------------
template <int MODE>
__global__ __launch_bounds__(256) void gemm_bt(
    const unsigned short* __restrict__ A, const unsigned short* __restrict__ B,
    void* __restrict__ Cv, int M, int N, int K, const int* __restrict__ flag)
{
  __shared__ __align__(16) short As[64 * 40];
  __shared__ __align__(16) short Bs[64 * 40];
  const int t = threadIdx.x;
  const int wave = t >> 6, lane = t & 63;
  const int quad = lane >> 4, l16 = lane & 15;
  const int m0 = blockIdx.y * 64, n0 = blockIdx.x * 64;
  const int srow = t >> 2, scol = (t & 3) * 8;
  f4 acc[4];
#pragma unroll
  for (int i = 0; i < 4; ++i) acc[i] = (f4){0.f, 0.f, 0.f, 0.f};
  const unsigned short* ap = A + (size_t)(m0 + srow) * K + scol;
  const unsigned short* bp = B + (size_t)(n0 + srow) * K + scol;
  for (int k0 = 0; k0 < K; k0 += 32) {
    uint4 av = *(const uint4*)(ap + k0);
    uint4 bv = *(const uint4*)(bp + k0);
    __syncthreads();
    *(uint4*)&As[srow * 40 + scol] = av;
    *(uint4*)&Bs[srow * 40 + scol] = bv;
    __syncthreads();
    bf16x8 af = *(const bf16x8*)&As[(wave * 16 + l16) * 40 + quad * 8];
#pragma unroll
    for (int nt = 0; nt < 4; ++nt) {
      bf16x8 bf = *(const bf16x8*)&Bs[(nt * 16 + l16) * 40 + quad * 8];
      acc[nt] = __builtin_amdgcn_mfma_f32_16x16x32_bf16(af, bf, acc[nt], 0, 0, 0);
    }
  }
  const int outf32 = (MODE == 0) ? 1 : (*flag ? 1 : 0);
#pragma unroll
  for (int nt = 0; nt < 4; ++nt) {
#pragma unroll
    for (int r = 0; r < 4; ++r) {
      int m = m0 + wave * 16 + quad * 4 + r;
      int n = n0 + nt * 16 + l16;
      if (outf32) ((float*)Cv)[(size_t)m * N + n] = acc[nt][r];
      else        ((unsigned short*)Cv)[(size_t)m * N + n] = f2b(acc[nt][r]);
    }
  }
}

// --------- per-head: dt=softplus(col)+A cumsum (reads fused GEMM cols) -----
__global__ __launch_bounds__(64) void cumsum_kernel(
    const float* __restrict__ qkvf, const float* __restrict__ smallf,
    float* __restrict__ dt_out, float* __restrict__ Ac)
{
  const int h = blockIdx.x;
  const int lane = threadIdx.x;
  const int base = lane * 32;
  const float dpb = smallf[9312 + h], dtb = smallf[9296 + h];
  const float nal = -expf(smallf[9280 + h]);
  float Av[32];
  float run = 0.f;
#pragma unroll
  for (int i = 0; i < 32; ++i) {
    const int l = base + i;
    float z = qkvf[(size_t)l * QKV_P + 3072 + h] + dpb + dtb;
    float dtv = (z > 20.f) ? z : log1pf(expf(z));
    dt_out[l * NH + h] = dtv;
    Av[i] = nal * dtv;
    run += Av[i];
  }
  float incl = run;
#pragma unroll
  for (int off = 1; off < 64; off <<= 1) {
    float n = __shfl_up(incl, off);
    if (lane >= off) incl += n;
  }
  float r2 = incl - run;
#pragma unroll
  for (int i = 0; i < 32; ++i) {
    r2 += Av[i];
    Ac[h * L_SEQ + base + i] = r2;
  }
}

// ------- fused conv: blocks <4096 do Q/K elementwise -> qc [L][2048];
//         blocks >=4096 do V conv + dt-scale + LDS transpose -> vt ---------
__global__ __launch_bounds__(256) void conv_kernel(
    const float* __restrict__ qkvf, const float* __restrict__ smallf,
    const float* __restrict__ dt, unsigned short* __restrict__ qc,
    unsigned short* __restrict__ vt)
{
  if (blockIdx.x < 4096) {
    const int idx = blockIdx.x * 256 + threadIdx.x;
    const int l = idx >> 9;                 // / 512
    const int c = (idx & 511) * 4;          // 0..2044
    f4 xc = *(const f4*)&qkvf[(size_t)l * QKV_P + c];
    f4 xp = (f4){0.f, 0.f, 0.f, 0.f};
    if (l > 0) xp = *(const f4*)&qkvf[(size_t)(l - 1) * QKV_P + c];
    const float* w; const float* b; int cb;
    if (c < HIDN) { w = smallf;        b = smallf + 2048; cb = c; }
    else          { w = smallf + 3072; b = smallf + 5120; cb = c - HIDN; }
    f4 o;
#pragma unroll
    for (int j = 0; j < 4; ++j)
      o[j] = b[cb + j] + xp[j] * w[(cb + j) * 2] + xc[j] * w[(cb + j) * 2 + 1];
    ushort4 st;
    st.x = f2h(o[0]); st.y = f2h(o[1]); st.z = f2h(o[2]); st.w = f2h(o[3]);
    *(ushort4*)&qc[(size_t)l * QC_S + c] = st;
  } else {
    __shared__ __align__(16) unsigned short Ts[64 * 68];
    const int bv = blockIdx.x - 4096;       // 0..511
    const int h = bv & 15;
    const int lt0 = bv >> 4;                // 0..31
    const int t = threadIdx.x;
    const int srow = t >> 2, cc = t & 3;
    const int l = lt0 * 64 + srow;
    const int cb = h * 64 + cc * 16;        // V-channel base (0..1023)
    const float* w = smallf + 6144;
    const float* b = smallf + 8192;
    const float dtv = dt[l * NH + h];
    const float* xcp = &qkvf[(size_t)l * QKV_P + 2048 + cb];
    const float* xpp = &qkvf[(size_t)(l - 1) * QKV_P + 2048 + cb];
    unsigned short o16[16];
#pragma unroll
    for (int g = 0; g < 4; ++g) {
      f4 xc = *(const f4*)(xcp + g * 4);
      f4 xp = (f4){0.f, 0.f, 0.f, 0.f};
      if (l > 0) xp = *(const f4*)(xpp + g * 4);
#pragma unroll
      for (int j = 0; j < 4; ++j) {
        const int ch = cb + g * 4 + j;
        float o = b[ch] + xp[j] * w[ch * 2] + xc[j] * w[ch * 2 + 1];
        o16[g * 4 + j] = f2h(o * dtv);
      }
    }
    *(uint4*)&Ts[srow * 68 + cc * 16]     = *(const uint4*)&o16[0];
    *(uint4*)&Ts[srow * 68 + cc * 16 + 8] = *(const uint4*)&o16[8];
    __syncthreads();
    __align__(16) unsigned short o[16];
#pragma unroll
    for (int j = 0; j < 16; ++j) o[j] = Ts[(cc * 16 + j) * 68 + srow];
    unsigned short* op = vt + ((size_t)h * DHD + srow) * L_SEQ + lt0 * 64 + cc * 16;
    *(uint4*)op = *(const uint4*)&o[0];
    *(uint4*)(op + 8) = *(const uint4*)&o[8];
  }
}

// ---------------- gated causal attention, barrier-free, split-m ------------
// grid 1024 blocks: n -> r=n&7 (XCD), q=n>>3: hh=q&1, s=(q>>1)&1, u=q>>2;
//   h = r + 8*hh; lt = u<16 ? u : 47-u; half s covers m-tiles
//   [0,ceil(nT/2)) or [ceil(nT/2), nT), nT = lt+1.
// K/V fragments are loaded DIRECTLY global->registers (no LDS staging, no
// double buffer, NO __syncthreads in the loop). Only LDS use: wave-private
// S roundtrip (same-wave RAW ordered by lgkmcnt). Each block writes fp32
// partial O to po[s]; reduce_kernel sums halves + RMSNorm (gate sum over m
// is linear -- no softmax normalization, so partials add exactly).
__global__ __launch_bounds__(256) void attn_kernel(
    const unsigned short* __restrict__ qc,     // fp16 [L][2048] (Q,K)
    const unsigned short* __restrict__ vt,     // fp16 [NH][DHD][L] (V^T)
    const float* __restrict__ Ac,              // [NH][L]
    const float* __restrict__ smallf,
    float* __restrict__ po)                    // fp32 [2][L][1024] partials
{
  const int n  = blockIdx.x;
  const int r_ = n & 7;
  const int q_ = n >> 3;
  const int hh = q_ & 1;
  const int s_ = (q_ >> 1) & 1;
  const int u  = q_ >> 2;
  const int h  = r_ + 8 * hh;
  const int lt = (u < 16) ? u : (47 - u);
  const int nT = lt + 1;
  const int mStart = s_ ? ((nT + 1) >> 1) : 0;
  const int mEnd   = s_ ? nT : ((nT + 1) >> 1);

  const int t  = threadIdx.x;
  const int w    = t >> 6;
  const int lane = t & 63;
  const int l16  = lane & 15;
  const int quad = lane >> 4;

  __shared__ __align__(16) unsigned short S_lds[64 * 68];  // S[l][m], wave-private rows

  const int l0 = lt * 64;
  const float rc = 1.0f / smallf[9328 + h];
  const float* Acp = Ac + h * L_SEQ;

  // Q A-fragments: row = l16, k(d) = ks*32 + quad*8 + j
  H8 qf0, qf1;
  {
    const unsigned short* qp =
        qc + (size_t)(l0 + w * 16 + l16) * QC_S + h * DHD + quad * 8;
    qf0.u4 = *(const uint4*)qp;
    qf1.u4 = *(const uint4*)(qp + 32);
  }
  float alv[4];
#pragma unroll
  for (int r = 0; r < 4; ++r) alv[r] = Acp[l0 + w * 16 + quad * 4 + r];

  f4 acc[4];
#pragma unroll
  for (int i = 0; i < 4; ++i) acc[i] = (f4){0.f, 0.f, 0.f, 0.f};

  // fragment base pointers (lane-dependent parts folded in)
  const unsigned short* kbase = qc + HIDN + h * DHD + quad * 8 + (size_t)l16 * QC_S;
  const unsigned short* vbase = vt + ((size_t)(h * DHD + l16)) * L_SEQ + quad * 8;

  uint4 kc[8];   // K frags for current tile: f = ks*4 + nt
  if (mStart < mEnd) {
    const int m0 = mStart * 64;
#pragma unroll
    for (int f = 0; f < 8; ++f) {
      const int nt = f & 3, ks = f >> 2;
      kc[f] = *(const uint4*)(kbase + (size_t)(m0 + nt * 16) * QC_S + ks * 32);
    }
  }

  for (int mt = mStart; mt < mEnd; ++mt) {
    const int m0 = mt * 64;
    // V frags for this tile (consumed at PV, ~500cy later -> latency hidden)
    uint4 vc[8];   // f = ks*4 + db
#pragma unroll
    for (int f = 0; f < 8; ++f) {
      const int db = f & 3, ks = f >> 2;
      vc[f] = *(const uint4*)(vbase + (size_t)(db * 16) * L_SEQ + m0 + ks * 32);
    }
    float amv[4];
#pragma unroll
    for (int nt = 0; nt < 4; ++nt) amv[nt] = Acp[m0 + nt * 16 + l16];
    // prefetch next K tile (consumed next iter)
    uint4 kn[8];
    const bool more = (mt + 1 < mEnd);
    if (more) {
      const int m1 = m0 + 64;
#pragma unroll
      for (int f = 0; f < 8; ++f) {
        const int nt = f & 3, ks = f >> 2;
        kn[f] = *(const uint4*)(kbase + (size_t)(m1 + nt * 16) * QC_S + ks * 32);
      }
    }

    // ---- QK^T ----
    f4 s[4];
#pragma unroll
    for (int i = 0; i < 4; ++i) s[i] = (f4){0.f, 0.f, 0.f, 0.f};
#pragma unroll
    for (int ks = 0; ks < 2; ++ks) {
      H8 qk = ks ? qf1 : qf0;
#pragma unroll
      for (int nt = 0; nt < 4; ++nt) {
        H8 kf; kf.u4 = kc[ks * 4 + nt];
        s[nt] = __builtin_amdgcn_mfma_f32_16x16x32_f16(qk.h, kf.h, s[nt], 0, 0, 0);
      }
    }
    // ---- gate + S write (wave-private rows) ----
#pragma unroll
    for (int nt = 0; nt < 4; ++nt) {
      const int mg = m0 + nt * 16 + l16;
      const float am = amv[nt];
#pragma unroll
      for (int r = 0; r < 4; ++r) {
        const int lg = l0 + w * 16 + quad * 4 + r;
        float val = (mg <= lg) ? s[nt][r] * __expf(alv[r] - am) * rc : 0.0f;
        S_lds[(w * 16 + quad * 4 + r) * 68 + nt * 16 + l16] = f2h(val);
      }
    }
    // ---- PV (same-wave S RAW: lgkmcnt orders it, no barrier) ----
#pragma unroll
    for (int ks = 0; ks < 2; ++ks) {
      H8 sa;
      const int so = (w * 16 + l16) * 68 + ks * 32 + quad * 8;
      sa.u2[0] = *(const u32x2*)&S_lds[so];
      sa.u2[1] = *(const u32x2*)&S_lds[so + 4];
#pragma unroll
      for (int db = 0; db < 4; ++db) {
        H8 vb; vb.u4 = vc[ks * 4 + db];
        acc[db] = __builtin_amdgcn_mfma_f32_16x16x32_f16(sa.h, vb.h, acc[db], 0, 0, 0);
      }
    }
    if (more) {
#pragma unroll
      for (int f = 0; f < 8; ++f) kc[f] = kn[f];
    }
  }

  // ---- write fp32 partials (RMSNorm deferred to reduce_kernel) ----
  float* pout = po + (size_t)s_ * (L_SEQ * HIDN);
#pragma unroll
  for (int r = 0; r < 4; ++r) {
    float* op = pout + (size_t)(l0 + w * 16 + quad * 4 + r) * HIDN + h * DHD + l16;
#pragma unroll
    for (int db = 0; db < 4; ++db)
      op[db * 16] = acc[db][r];
  }
}

// ------- reduce: po0+po1, RMSNorm over d=64, bf16 store --------------------
__global__ __launch_bounds__(256) void reduce_kernel(
    const float* __restrict__ po, const float* __restrict__ smallf,
    unsigned short* __restrict__ attn_out)
{
  const int l = blockIdx.x;
  const int t = threadIdx.x;
  const int col = t * 4;
  const float* p0 = po + (size_t)l * HIDN + col;
  const float* p1 = p0 + (size_t)L_SEQ * HIDN;
  f4 a = *(const f4*)p0;
  f4 b = *(const f4*)p1;
  f4 o = a + b;
  float p = o[0] * o[0] + o[1] * o[1] + o[2] * o[2] + o[3] * o[3];
#pragma unroll
  for (int off = 1; off < 16; off <<= 1) p += __shfl_xor(p, off);
  const float rn = rsqrtf(p * (1.0f / 64.0f) + 1.1920928955078125e-07f);
  const int d0 = col & 63;
  ushort4 st;
  st.x = f2b(o[0] * rn * smallf[9216 + d0]);
  st.y = f2b(o[1] * rn * smallf[9216 + d0 + 1]);
  st.z = f2b(o[2] * rn * smallf[9216 + d0 + 2]);
  st.w = f2b(o[3] * rn * smallf[9216 + d0 + 3]);
  *(ushort4*)&attn_out[(size_t)l * HIDN + col] = st;
}

extern "C" void kernel_launch(void* const* d_in, const int* in_sizes, int n_in,
                              void* d_out, int out_size, void* d_ws, size_t ws_size,
                              hipStream_t stream)
{
  (void)in_sizes; (void)n_in; (void)out_size; (void)ws_size;
  const void* hs        = d_in[0];
  // d_in[1] = attention_mask: deterministic causal triu — handled analytically
  const void* qkv_w     = d_in[2];
  const void* q_conv_w  = d_in[3];
  const void* q_conv_b  = d_in[4];
  const void* k_conv_w  = d_in[5];
  const void* k_conv_b  = d_in[6];
  const void* v_conv_w  = d_in[7];
  const void* v_conv_b  = d_in[8];
  const void* norm_w    = d_in[9];
  const void* A_log     = d_in[10];
  const void* dt_bias   = d_in[11];
  const void* dt_proj_w = d_in[12];
  const void* dt_proj_b = d_in[13];
  const void* o_w       = d_in[14];
  const void* ordc      = d_in[15];

  char* ws = (char*)d_ws;
  int* flag             = (int*)ws;                              // @0
  unsigned short* hs_b  = (unsigned short*)(ws + 256);           // 4,194,304
  unsigned short* qkvw_b= (unsigned short*)(ws + 4194560);       // 6,553,600 ([3200][1024])
  unsigned short* ow_b  = (unsigned short*)(ws + 10748160);      // 2,097,152
  float* smallf         = (float*)(ws + 12845312);               // 37,376
  float* qkvf           = (float*)(ws + 12882688);               // 26,214,400 ([2048][3200] f32)
  unsigned short* qc_h  = (unsigned short*)(ws + 39097088);      // 8,388,608 ([2048][2048] f16)
  float* dtbuf          = (float*)(ws + 47485696);               // 131,072
  float* Acum           = (float*)(ws + 47616768);               // 131,072
  unsigned short* attnb = (unsigned short*)(ws + 47747840);      // 4,194,304
  unsigned short* vt_h  = (unsigned short*)(ws + 51942144);      // 4,194,304
  float* po             = (float*)(ws + 56136448);               // 16,777,216 ([2][2048][1024] f32)

  prep_kernel<<<1024, 256, 0, stream>>>(
      hs, qkv_w, o_w, dt_proj_w,
      q_conv_w, q_conv_b, k_conv_w, k_conv_b, v_conv_w, v_conv_b,
      norm_w, A_log, dt_bias, dt_proj_b, ordc,
      hs_b, qkvw_b, ow_b, smallf, flag);

  gemm128<<<dim3(QKV_P / 128, L_SEQ / 128), 256, 0, stream>>>(
      hs_b, qkvw_b, qkvf, L_SEQ, QKV_P, HIDN);
  cumsum_kernel<<<NH, 64, 0, stream>>>(qkvf, smallf, dtbuf, Acum);
  conv_kernel<<<4096 + 512, 256, 0, stream>>>(qkvf, smallf, dtbuf, qc_h, vt_h);
  attn_kernel<<<1024, 256, 0, stream>>>(qc_h, vt_h, Acum, smallf, po);
  reduce_kernel<<<L_SEQ, 256, 0, stream>>>(po, smallf, attnb);
  gemm_bt<1><<<dim3(HIDN / 64, L_SEQ / 64), 256, 0, stream>>>(
      attnb, ow_b, d_out, L_SEQ, HIDN, HIDN, flag);
}

// Round 11
// 236.537 us; speedup vs baseline: 1.1621x; 1.1621x over previous
//
#include <hip/hip_runtime.h>
#include <hip/hip_bf16.h>

#define L_SEQ 2048
#define HIDN  1024
#define NH    16
#define DHD   64
#define QKV_P 3200   // padded GEMM N: 3072 qkv + 16 dt rows + 112 pad
#define QC_S  2048   // qc stride: Q(1024) + K(1024); V goes to vt
#define LP    72     // LDS row pitch (elems): 144B = 16B-aligned rows

typedef float f4 __attribute__((ext_vector_type(4)));
typedef __bf16 bf16x8 __attribute__((ext_vector_type(8)));
typedef _Float16 half8 __attribute__((ext_vector_type(8)));

union H8 {
  half8 h;
  uint4 u4;
};

__device__ __forceinline__ float b2f(unsigned short u) {
  union { unsigned int i; float f; } c; c.i = ((unsigned int)u) << 16; return c.f;
}
__device__ __forceinline__ unsigned short f2b(float f) {
  union { float f; unsigned int i; } c; c.f = f;
  unsigned int r = c.i + 0x7FFFu + ((c.i >> 16) & 1u);
  return (unsigned short)(r >> 16);
}
__device__ __forceinline__ unsigned short f2h(float f) {
  union { _Float16 h; unsigned short u; } c; c.h = (_Float16)f; return c.u;
}

// ------------- fused prep: dtype detect + canonicalize all params ----------
// qkvw_b is [3200][1024] bf16: rows 0-3071 = qkv_w, 3072-3087 = dt_proj_w,
// 3088-3199 = zeros. smallf layout: qw@0(2048) qb@2048(1024) kw@3072(2048)
// kb@5120(1024) vw@6144(2048) vb@8192(1024) nw@9216(64) al@9280(16)
// dt_bias@9296(16) dt_proj_b@9312(16) oc@9328(16)  total 9344
__global__ __launch_bounds__(256) void prep_kernel(
    const void* hs, const void* qkvw, const void* ow, const void* dtw,
    const void* qw, const void* qb, const void* kw, const void* kb,
    const void* vw, const void* vb, const void* nw, const void* al,
    const void* dtb, const void* dpb, const void* oc,
    unsigned short* __restrict__ hs_b, unsigned short* __restrict__ qkvw_b,
    unsigned short* __restrict__ ow_b,
    float* __restrict__ smallf, int* __restrict__ flag)
{
  __shared__ int cnt;
  if (threadIdx.x == 0) cnt = 0;
  __syncthreads();
  {
    const unsigned short* p = (const unsigned short*)hs;
    int c = 0;
    for (int i = threadIdx.x; i < 8192; i += 256)
      if (((p[i] >> 7) & 0xFFu) >= 140u) c++;
    atomicAdd(&cnt, c);
  }
  __syncthreads();
  const int f = (cnt >= 32) ? 1 : 0;          // 1 = fp32 inputs
  if (blockIdx.x == 0 && threadIdx.x == 0) *flag = f;

  const int tid = blockIdx.x * 256 + threadIdx.x;
  const int nth = gridDim.x * 256;
  // 4-elem groups: hs 524288 | qkvw 786432 | dtw 4096 | pad 28672 | ow 262144
  for (int i = tid; i < 1605632; i += nth) {
    const void* src; unsigned short* dst; int off;
    if (i < 524288)       { src = hs;   dst = hs_b;   off = i; }
    else if (i < 1310720) { src = qkvw; dst = qkvw_b; off = i - 524288; }
    else if (i < 1314816) { src = dtw;  dst = qkvw_b + 3072 * 1024; off = i - 1310720; }
    else if (i < 1343488) {  // zero pad rows 3088-3199
      *(ushort4*)(qkvw_b + 3088 * 1024 + (i - 1314816) * 4) = (ushort4){0, 0, 0, 0};
      continue;
    }
    else                  { src = ow;   dst = ow_b;   off = i - 1343488; }
    const int e = off * 4;
    if (f) {
      f4 v = *(const f4*)((const float*)src + e);
      ushort4 o;
      o.x = f2b(v[0]); o.y = f2b(v[1]); o.z = f2b(v[2]); o.w = f2b(v[3]);
      *(ushort4*)(dst + e) = o;
    } else {
      *(uint2*)(dst + e) = *(const uint2*)((const unsigned short*)src + e);
    }
  }
  const void* ptrs[11] = {qw, qb, kw, kb, vw, vb, nw, al, dtb, dpb, oc};
  const int sizes[11] = {2048, 1024, 2048, 1024, 2048, 1024, 64, 16, 16, 16, 16};
  int off = 0;
  for (int a = 0; a < 11; ++a) {
    for (int i = tid; i < sizes[a]; i += nth)
      smallf[off + i] = f ? ((const float*)ptrs[a])[i]
                          : b2f(((const unsigned short*)ptrs[a])[i]);
    off += sizes[a];
  }
}

// ------- C = A (MxK) * B^T (NxK), bf16 in, fp32 out, 128x128 tile ---------
__global__ __launch_bounds__(256) void gemm128(
    const unsigned short* __restrict__ A, const unsigned short* __restrict__ B,
    float* __restrict__ C, int M, int N, int K)
{
  __shared__ __align__(16) unsigned short As[128 * 40];
  __shared__ __align__(16) unsigned short Bs[128 * 40];
  const int t = threadIdx.x;
  const int w = t >> 6, lane = t & 63;
  const int quad = lane >> 4, l16 = lane & 15;
  const int wr = w >> 1, wc = w & 1;
  const int m0 = blockIdx.y * 128, n0 = blockIdx.x * 128;
  const int srow = t >> 1;
  const int scol = (t & 1) * 16;

  f4 acc[4][4];
#pragma unroll
  for (int i = 0; i < 4; ++i)
#pragma unroll
    for (int j = 0; j < 4; ++j) acc[i][j] = (f4){0.f, 0.f, 0.f, 0.f};

  const unsigned short* apg = A + (size_t)(m0 + srow) * K + scol;
  const unsigned short* bpg = B + (size_t)(n0 + srow) * K + scol;
  uint4 a0 = *(const uint4*)apg,       a1 = *(const uint4*)(apg + 8);
  uint4 b0 = *(const uint4*)bpg,       b1 = *(const uint4*)(bpg + 8);

  for (int k0 = 0; k0 < K; k0 += 32) {
    __syncthreads();
    *(uint4*)&As[srow * 40 + scol]     = a0;
    *(uint4*)&As[srow * 40 + scol + 8] = a1;
    *(uint4*)&Bs[srow * 40 + scol]     = b0;
    *(uint4*)&Bs[srow * 40 + scol + 8] = b1;
    __syncthreads();
    if (k0 + 32 < K) {
      a0 = *(const uint4*)(apg + k0 + 32); a1 = *(const uint4*)(apg + k0 + 40);
      b0 = *(const uint4*)(bpg + k0 + 32); b1 = *(const uint4*)(bpg + k0 + 40);
    }
    bf16x8 aF[4], bF[4];
#pragma unroll
    for (int i = 0; i < 4; ++i)
      aF[i] = *(const bf16x8*)&As[(wr * 64 + i * 16 + l16) * 40 + quad * 8];
#pragma unroll
    for (int j = 0; j < 4; ++j)
      bF[j] = *(const bf16x8*)&Bs[(wc * 64 + j * 16 + l16) * 40 + quad * 8];
#pragma unroll
    for (int i = 0; i < 4; ++i)
#pragma unroll
      for (int j = 0; j < 4; ++j)
        acc[i][j] = __builtin_amdgcn_mfma_f32_16x16x32_bf16(aF[i], bF[j], acc[i][j], 0, 0, 0);
  }

#pragma unroll
  for (int i = 0; i < 4; ++i)
#pragma unroll
    for (int j = 0; j < 4; ++j)
#pragma unroll
      for (int r = 0; r < 4; ++r) {
        int m = m0 + wr * 64 + i * 16 + quad * 4 + r;
        int n = n0 + wc * 64 + j * 16 + l16;
        C[(size_t)m * N + n] = acc[i][j][r];
      }
}

// ---------------- C = A (MxK) * B^T (NxK), bf16 in, 64x64 tile --------------
template <int MODE>
__global__ __launch_bounds__(256) void gemm_bt(
    const unsigned short* __restrict__ A, const unsigned short* __restrict__ B,
    void* __restrict__ Cv, int M, int N, int K, const int* __restrict__ flag)
{
  __shared__ __align__(16) short As[64 * 40];
  __shared__ __align__(16) short Bs[64 * 40];
  const int t = threadIdx.x;
  const int wave = t >> 6, lane = t & 63;
  const int quad = lane >> 4, l16 = lane & 15;
  const int m0 = blockIdx.y * 64, n0 = blockIdx.x * 64;
  const int srow = t >> 2, scol = (t & 3) * 8;
  f4 acc[4];
#pragma unroll
  for (int i = 0; i < 4; ++i) acc[i] = (f4){0.f, 0.f, 0.f, 0.f};
  const unsigned short* ap = A + (size_t)(m0 + srow) * K + scol;
  const unsigned short* bp = B + (size_t)(n0 + srow) * K + scol;
  for (int k0 = 0; k0 < K; k0 += 32) {
    uint4 av = *(const uint4*)(ap + k0);
    uint4 bv = *(const uint4*)(bp + k0);
    __syncthreads();
    *(uint4*)&As[srow * 40 + scol] = av;
    *(uint4*)&Bs[srow * 40 + scol] = bv;
    __syncthreads();
    bf16x8 af = *(const bf16x8*)&As[(wave * 16 + l16) * 40 + quad * 8];
#pragma unroll
    for (int nt = 0; nt < 4; ++nt) {
      bf16x8 bf = *(const bf16x8*)&Bs[(nt * 16 + l16) * 40 + quad * 8];
      acc[nt] = __builtin_amdgcn_mfma_f32_16x16x32_bf16(af, bf, acc[nt], 0, 0, 0);
    }
  }
  const int outf32 = (MODE == 0) ? 1 : (*flag ? 1 : 0);
#pragma unroll
  for (int nt = 0; nt < 4; ++nt) {
#pragma unroll
    for (int r = 0; r < 4; ++r) {
      int m = m0 + wave * 16 + quad * 4 + r;
      int n = n0 + nt * 16 + l16;
      if (outf32) ((float*)Cv)[(size_t)m * N + n] = acc[nt][r];
      else        ((unsigned short*)Cv)[(size_t)m * N + n] = f2b(acc[nt][r]);
    }
  }
}

// --------- per-head: dt=softplus(col)+A cumsum (reads fused GEMM cols) -----
__global__ __launch_bounds__(64) void cumsum_kernel(
    const float* __restrict__ qkvf, const float* __restrict__ smallf,
    float* __restrict__ dt_out, float* __restrict__ Ac)
{
  const int h = blockIdx.x;
  const int lane = threadIdx.x;
  const int base = lane * 32;
  const float dpb = smallf[9312 + h], dtb = smallf[9296 + h];
  const float nal = -expf(smallf[9280 + h]);
  float Av[32];
  float run = 0.f;
#pragma unroll
  for (int i = 0; i < 32; ++i) {
    const int l = base + i;
    float z = qkvf[(size_t)l * QKV_P + 3072 + h] + dpb + dtb;
    float dtv = (z > 20.f) ? z : log1pf(expf(z));
    dt_out[l * NH + h] = dtv;
    Av[i] = nal * dtv;
    run += Av[i];
  }
  float incl = run;
#pragma unroll
  for (int off = 1; off < 64; off <<= 1) {
    float n = __shfl_up(incl, off);
    if (lane >= off) incl += n;
  }
  float r2 = incl - run;
#pragma unroll
  for (int i = 0; i < 32; ++i) {
    r2 += Av[i];
    Ac[h * L_SEQ + base + i] = r2;
  }
}

// ------- fused conv: blocks <4096 do Q/K elementwise -> qc [L][2048];
//         blocks >=4096 do V conv + dt-scale + LDS transpose -> vt ---------
__global__ __launch_bounds__(256) void conv_kernel(
    const float* __restrict__ qkvf, const float* __restrict__ smallf,
    const float* __restrict__ dt, unsigned short* __restrict__ qc,
    unsigned short* __restrict__ vt)
{
  if (blockIdx.x < 4096) {
    const int idx = blockIdx.x * 256 + threadIdx.x;
    const int l = idx >> 9;                 // / 512
    const int c = (idx & 511) * 4;          // 0..2044
    f4 xc = *(const f4*)&qkvf[(size_t)l * QKV_P + c];
    f4 xp = (f4){0.f, 0.f, 0.f, 0.f};
    if (l > 0) xp = *(const f4*)&qkvf[(size_t)(l - 1) * QKV_P + c];
    const float* w; const float* b; int cb;
    if (c < HIDN) { w = smallf;        b = smallf + 2048; cb = c; }
    else          { w = smallf + 3072; b = smallf + 5120; cb = c - HIDN; }
    f4 o;
#pragma unroll
    for (int j = 0; j < 4; ++j)
      o[j] = b[cb + j] + xp[j] * w[(cb + j) * 2] + xc[j] * w[(cb + j) * 2 + 1];
    ushort4 st;
    st.x = f2h(o[0]); st.y = f2h(o[1]); st.z = f2h(o[2]); st.w = f2h(o[3]);
    *(ushort4*)&qc[(size_t)l * QC_S + c] = st;
  } else {
    __shared__ __align__(16) unsigned short Ts[64 * 68];
    const int bv = blockIdx.x - 4096;       // 0..511
    const int h = bv & 15;
    const int lt0 = bv >> 4;                // 0..31
    const int t = threadIdx.x;
    const int srow = t >> 2, cc = t & 3;
    const int l = lt0 * 64 + srow;
    const int cb = h * 64 + cc * 16;        // V-channel base (0..1023)
    const float* w = smallf + 6144;
    const float* b = smallf + 8192;
    const float dtv = dt[l * NH + h];
    const float* xcp = &qkvf[(size_t)l * QKV_P + 2048 + cb];
    const float* xpp = &qkvf[(size_t)(l - 1) * QKV_P + 2048 + cb];
    unsigned short o16[16];
#pragma unroll
    for (int g = 0; g < 4; ++g) {
      f4 xc = *(const f4*)(xcp + g * 4);
      f4 xp = (f4){0.f, 0.f, 0.f, 0.f};
      if (l > 0) xp = *(const f4*)(xpp + g * 4);
#pragma unroll
      for (int j = 0; j < 4; ++j) {
        const int ch = cb + g * 4 + j;
        float o = b[ch] + xp[j] * w[ch * 2] + xc[j] * w[ch * 2 + 1];
        o16[g * 4 + j] = f2h(o * dtv);
      }
    }
    *(uint4*)&Ts[srow * 68 + cc * 16]     = *(const uint4*)&o16[0];
    *(uint4*)&Ts[srow * 68 + cc * 16 + 8] = *(const uint4*)&o16[8];
    __syncthreads();
    __align__(16) unsigned short o[16];
#pragma unroll
    for (int j = 0; j < 16; ++j) o[j] = Ts[(cc * 16 + j) * 68 + srow];
    unsigned short* op = vt + ((size_t)h * DHD + srow) * L_SEQ + lt0 * 64 + cc * 16;
    *(uint4*)op = *(const uint4*)&o[0];
    *(uint4*)(op + 8) = *(const uint4*)&o[8];
  }
}

// ---------------- gated causal attention + RMSNorm (MFMA fp16) -------------
// grid (32, NH) -> 512 blocks; XCD-aware BALANCED remap:
//   n = bx + 32*by; r = n&7 (XCD under round-robin %8); q = n>>3;
//   h = r + 8*(q&1); v = q>>1; lt = v<16 ? v : 47-v.
// Co-resident pair (n, n+256): same r (same XCD), same q&1 (same head ->
// L1/L2 reuse), v differs by 16 -> lt complementary (sum 31) -> every CU
// runs exactly 33 iters. Each XCD owns heads {r, r+8}: K/V fill ONE L2.
// LDS pitch 72 (144B rows, 16B-aligned): staging = b128 writes, all
// fragment reads = single ds_read_b128 (bank-uniform). 38 DS instr/wave/iter
// (was 60). Causal compare only on the diagonal tile.
// Loop order [prefetch][compute][stage][barrier] (T14).
__global__ __launch_bounds__(256) void attn_kernel(
    const unsigned short* __restrict__ qc,     // fp16 [L][2048] (Q,K)
    const unsigned short* __restrict__ vt,     // fp16 [NH][DHD][L] (V^T)
    const float* __restrict__ Ac,              // [NH][L]
    const float* __restrict__ smallf,
    unsigned short* __restrict__ attn_out)     // bf16 [L][1024]
{
  const int n  = blockIdx.x + 32 * blockIdx.y;
  const int r_ = n & 7;
  const int q_ = n >> 3;
  const int h  = r_ + 8 * (q_ & 1);
  const int v_ = q_ >> 1;
  const int lt = (v_ < 16) ? v_ : (47 - v_);
  const int t  = threadIdx.x;
  const int w    = t >> 6;
  const int lane = t & 63;
  const int l16  = lane & 15;
  const int quad = lane >> 4;
  const int srow = t >> 2;
  const int cc   = t & 3;

  __shared__ __align__(16) unsigned short K_lds[2][64 * LP];  // K[m][d]
  __shared__ __align__(16) unsigned short V_lds[2][64 * LP];  // V^T[d][m]
  __shared__ __align__(16) unsigned short S_lds[64 * LP];     // S[l][m]

  const int l0 = lt * 64;
  const float rc = 1.0f / smallf[9328 + h];
  const float* Acp = Ac + h * L_SEQ;

  H8 qf0, qf1;
  {
    const unsigned short* qp =
        qc + (size_t)(l0 + w * 16 + l16) * QC_S + h * DHD + quad * 8;
    qf0.u4 = *(const uint4*)qp;
    qf1.u4 = *(const uint4*)(qp + 32);
  }
  float alv[4];
#pragma unroll
  for (int r = 0; r < 4; ++r) alv[r] = Acp[l0 + w * 16 + quad * 4 + r];

  f4 acc[4];
#pragma unroll
  for (int i = 0; i < 4; ++i) acc[i] = (f4){0.f, 0.f, 0.f, 0.f};

  const unsigned short* kgp =
      qc + (size_t)srow * QC_S + HIDN + h * DHD + cc * 16;
  const unsigned short* vgp =
      vt + ((size_t)h * DHD + srow) * L_SEQ + cc * 16;

  const int swo = srow * LP + cc * 16;

  uint4 k0v = *(const uint4*)kgp,       k1v = *(const uint4*)(kgp + 8);
  uint4 v0v = *(const uint4*)vgp,       v1v = *(const uint4*)(vgp + 8);
  float amv[4];
#pragma unroll
  for (int nt = 0; nt < 4; ++nt) amv[nt] = Acp[nt * 16 + l16];

  *(uint4*)&K_lds[0][swo]     = k0v;
  *(uint4*)&K_lds[0][swo + 8] = k1v;
  *(uint4*)&V_lds[0][swo]     = v0v;
  *(uint4*)&V_lds[0][swo + 8] = v1v;
  __syncthreads();

  int cur = 0;
  for (int it = 0; it <= lt; ++it) {
    uint4 nk0 = k0v, nk1 = k1v, nv0 = v0v, nv1 = v1v;
    float namv[4];
    const bool more = (it < lt);
    if (more) {
      const unsigned short* kp = kgp + (size_t)(it + 1) * 64 * QC_S;
      const unsigned short* vp = vgp + (size_t)(it + 1) * 64;
      nk0 = *(const uint4*)kp; nk1 = *(const uint4*)(kp + 8);
      nv0 = *(const uint4*)vp; nv1 = *(const uint4*)(vp + 8);
#pragma unroll
      for (int nt = 0; nt < 4; ++nt)
        namv[nt] = Acp[(it + 1) * 64 + nt * 16 + l16];
    }

    // ---- QK^T (b128 fragment reads) ----
    f4 s[4];
#pragma unroll
    for (int i = 0; i < 4; ++i) s[i] = (f4){0.f, 0.f, 0.f, 0.f};
#pragma unroll
    for (int ks = 0; ks < 2; ++ks) {
      H8 qk = ks ? qf1 : qf0;
#pragma unroll
      for (int nt = 0; nt < 4; ++nt) {
        H8 kf;
        kf.u4 = *(const uint4*)&K_lds[cur][(nt * 16 + l16) * LP + ks * 32 + quad * 8];
        s[nt] = __builtin_amdgcn_mfma_f32_16x16x32_f16(qk.h, kf.h, s[nt], 0, 0, 0);
      }
    }
    // ---- gate + S write (causal compare only on diagonal tile) ----
    const int m0 = it * 64;
    if (it == lt) {
#pragma unroll
      for (int nt = 0; nt < 4; ++nt) {
        const int mg = m0 + nt * 16 + l16;
        const float am = amv[nt];
#pragma unroll
        for (int r = 0; r < 4; ++r) {
          const int lg = l0 + w * 16 + quad * 4 + r;
          float val = (mg <= lg) ? s[nt][r] * __expf(alv[r] - am) * rc : 0.0f;
          S_lds[(w * 16 + quad * 4 + r) * LP + nt * 16 + l16] = f2h(val);
        }
      }
    } else {
#pragma unroll
      for (int nt = 0; nt < 4; ++nt) {
        const float am = amv[nt];
#pragma unroll
        for (int r = 0; r < 4; ++r) {
          float val = s[nt][r] * __expf(alv[r] - am) * rc;
          S_lds[(w * 16 + quad * 4 + r) * LP + nt * 16 + l16] = f2h(val);
        }
      }
    }
    // ---- PV (wave-private S rows; b128 reads) ----
#pragma unroll
    for (int ks = 0; ks < 2; ++ks) {
      H8 sa;
      sa.u4 = *(const uint4*)&S_lds[(w * 16 + l16) * LP + ks * 32 + quad * 8];
#pragma unroll
      for (int db = 0; db < 4; ++db) {
        H8 vb;
        vb.u4 = *(const uint4*)&V_lds[cur][(db * 16 + l16) * LP + ks * 32 + quad * 8];
        acc[db] = __builtin_amdgcn_mfma_f32_16x16x32_f16(sa.h, vb.h, acc[db], 0, 0, 0);
      }
    }
    // ---- stage next tile (b128) + one barrier ----
    if (more) {
      unsigned short* Kl = K_lds[cur ^ 1];
      unsigned short* Vl = V_lds[cur ^ 1];
      *(uint4*)&Kl[swo]     = nk0;
      *(uint4*)&Kl[swo + 8] = nk1;
      *(uint4*)&Vl[swo]     = nv0;
      *(uint4*)&Vl[swo + 8] = nv1;
#pragma unroll
      for (int nt = 0; nt < 4; ++nt) amv[nt] = namv[nt];
      __syncthreads();
      cur ^= 1;
    }
  }

  // ---- RMSNorm over d=64 and bf16 store ----
#pragma unroll
  for (int r = 0; r < 4; ++r) {
    float p = acc[0][r] * acc[0][r] + acc[1][r] * acc[1][r]
            + acc[2][r] * acc[2][r] + acc[3][r] * acc[3][r];
#pragma unroll
    for (int off = 1; off < 16; off <<= 1) p += __shfl_xor(p, off);
    const float rn = rsqrtf(p * (1.0f / 64.0f) + 1.1920928955078125e-07f);
    unsigned short* op =
        attn_out + (size_t)(l0 + w * 16 + quad * 4 + r) * HIDN + h * DHD + l16;
#pragma unroll
    for (int ds = 0; ds < 4; ++ds)
      op[ds * 16] = f2b(acc[ds][r] * rn * smallf[9216 + ds * 16 + l16]);
  }
}

extern "C" void kernel_launch(void* const* d_in, const int* in_sizes, int n_in,
                              void* d_out, int out_size, void* d_ws, size_t ws_size,
                              hipStream_t stream)
{
  (void)in_sizes; (void)n_in; (void)out_size; (void)ws_size;
  const void* hs        = d_in[0];
  // d_in[1] = attention_mask: deterministic causal triu — handled analytically
  const void* qkv_w     = d_in[2];
  const void* q_conv_w  = d_in[3];
  const void* q_conv_b  = d_in[4];
  const void* k_conv_w  = d_in[5];
  const void* k_conv_b  = d_in[6];
  const void* v_conv_w  = d_in[7];
  const void* v_conv_b  = d_in[8];
  const void* norm_w    = d_in[9];
  const void* A_log     = d_in[10];
  const void* dt_bias   = d_in[11];
  const void* dt_proj_w = d_in[12];
  const void* dt_proj_b = d_in[13];
  const void* o_w       = d_in[14];
  const void* ordc      = d_in[15];

  char* ws = (char*)d_ws;
  int* flag             = (int*)ws;                              // @0
  unsigned short* hs_b  = (unsigned short*)(ws + 256);           // 4,194,304
  unsigned short* qkvw_b= (unsigned short*)(ws + 4194560);       // 6,553,600 ([3200][1024])
  unsigned short* ow_b  = (unsigned short*)(ws + 10748160);      // 2,097,152
  float* smallf         = (float*)(ws + 12845312);               // 37,376
  float* qkvf           = (float*)(ws + 12882688);               // 26,214,400 ([2048][3200] f32)
  unsigned short* qc_h  = (unsigned short*)(ws + 39097088);      // 8,388,608 ([2048][2048] f16)
  float* dtbuf          = (float*)(ws + 47485696);               // 131,072
  float* Acum           = (float*)(ws + 47616768);               // 131,072
  unsigned short* attnb = (unsigned short*)(ws + 47747840);      // 4,194,304
  unsigned short* vt_h  = (unsigned short*)(ws + 51942144);      // 4,194,304

  prep_kernel<<<1024, 256, 0, stream>>>(
      hs, qkv_w, o_w, dt_proj_w,
      q_conv_w, q_conv_b, k_conv_w, k_conv_b, v_conv_w, v_conv_b,
      norm_w, A_log, dt_bias, dt_proj_b, ordc,
      hs_b, qkvw_b, ow_b, smallf, flag);

  gemm128<<<dim3(QKV_P / 128, L_SEQ / 128), 256, 0, stream>>>(
      hs_b, qkvw_b, qkvf, L_SEQ, QKV_P, HIDN);
  cumsum_kernel<<<NH, 64, 0, stream>>>(qkvf, smallf, dtbuf, Acum);
  conv_kernel<<<4096 + 512, 256, 0, stream>>>(qkvf, smallf, dtbuf, qc_h, vt_h);
  attn_kernel<<<dim3(32, NH), 256, 0, stream>>>(qc_h, vt_h, Acum, smallf, attnb);
  gemm_bt<1><<<dim3(HIDN / 64, L_SEQ / 64), 256, 0, stream>>>(
      attnb, ow_b, d_out, L_SEQ, HIDN, HIDN, flag);
}

// Round 12
// 220.692 us; speedup vs baseline: 1.2456x; 1.0718x over previous
//
#include <hip/hip_runtime.h>
#include <hip/hip_bf16.h>

#define L_SEQ 2048
#define HIDN  1024
#define NH    16
#define DHD   64
#define QKV_P 3200   // padded GEMM N: 3072 qkv + 16 dt rows + 112 pad
#define QC_S  2048   // qc stride: Q(1024) + K(1024); V goes to vt
#define LP    72     // LDS row pitch (elems): 144B = 16B-aligned rows

typedef float f4 __attribute__((ext_vector_type(4)));
typedef __bf16 bf16x8 __attribute__((ext_vector_type(8)));
typedef _Float16 half8 __attribute__((ext_vector_type(8)));

union H8 {
  half8 h;
  uint4 u4;
};

__device__ __forceinline__ float b2f(unsigned short u) {
  union { unsigned int i; float f; } c; c.i = ((unsigned int)u) << 16; return c.f;
}
__device__ __forceinline__ unsigned short f2b(float f) {
  union { float f; unsigned int i; } c; c.f = f;
  unsigned int r = c.i + 0x7FFFu + ((c.i >> 16) & 1u);
  return (unsigned short)(r >> 16);
}
__device__ __forceinline__ unsigned short f2h(float f) {
  union { _Float16 h; unsigned short u; } c; c.h = (_Float16)f; return c.u;
}

// ------------- fused prep: dtype detect + canonicalize all params ----------
// qkvw_b is [3200][1024] bf16: rows 0-3071 = qkv_w, 3072-3087 = dt_proj_w,
// 3088-3199 = zeros. smallf layout: qw@0(2048) qb@2048(1024) kw@3072(2048)
// kb@5120(1024) vw@6144(2048) vb@8192(1024) nw@9216(64) al@9280(16)
// dt_bias@9296(16) dt_proj_b@9312(16) oc@9328(16)  total 9344
__global__ __launch_bounds__(256) void prep_kernel(
    const void* hs, const void* qkvw, const void* ow, const void* dtw,
    const void* qw, const void* qb, const void* kw, const void* kb,
    const void* vw, const void* vb, const void* nw, const void* al,
    const void* dtb, const void* dpb, const void* oc,
    unsigned short* __restrict__ hs_b, unsigned short* __restrict__ qkvw_b,
    unsigned short* __restrict__ ow_b,
    float* __restrict__ smallf, int* __restrict__ flag)
{
  __shared__ int cnt;
  if (threadIdx.x == 0) cnt = 0;
  __syncthreads();
  {
    const unsigned short* p = (const unsigned short*)hs;
    int c = 0;
    for (int i = threadIdx.x; i < 8192; i += 256)
      if (((p[i] >> 7) & 0xFFu) >= 140u) c++;
    atomicAdd(&cnt, c);
  }
  __syncthreads();
  const int f = (cnt >= 32) ? 1 : 0;          // 1 = fp32 inputs
  if (blockIdx.x == 0 && threadIdx.x == 0) *flag = f;

  const int tid = blockIdx.x * 256 + threadIdx.x;
  const int nth = gridDim.x * 256;
  // 4-elem groups: hs 524288 | qkvw 786432 | dtw 4096 | pad 28672 | ow 262144
  for (int i = tid; i < 1605632; i += nth) {
    const void* src; unsigned short* dst; int off;
    if (i < 524288)       { src = hs;   dst = hs_b;   off = i; }
    else if (i < 1310720) { src = qkvw; dst = qkvw_b; off = i - 524288; }
    else if (i < 1314816) { src = dtw;  dst = qkvw_b + 3072 * 1024; off = i - 1310720; }
    else if (i < 1343488) {  // zero pad rows 3088-3199
      *(ushort4*)(qkvw_b + 3088 * 1024 + (i - 1314816) * 4) = (ushort4){0, 0, 0, 0};
      continue;
    }
    else                  { src = ow;   dst = ow_b;   off = i - 1343488; }
    const int e = off * 4;
    if (f) {
      f4 v = *(const f4*)((const float*)src + e);
      ushort4 o;
      o.x = f2b(v[0]); o.y = f2b(v[1]); o.z = f2b(v[2]); o.w = f2b(v[3]);
      *(ushort4*)(dst + e) = o;
    } else {
      *(uint2*)(dst + e) = *(const uint2*)((const unsigned short*)src + e);
    }
  }
  const void* ptrs[11] = {qw, qb, kw, kb, vw, vb, nw, al, dtb, dpb, oc};
  const int sizes[11] = {2048, 1024, 2048, 1024, 2048, 1024, 64, 16, 16, 16, 16};
  int off = 0;
  for (int a = 0; a < 11; ++a) {
    for (int i = tid; i < sizes[a]; i += nth)
      smallf[off + i] = f ? ((const float*)ptrs[a])[i]
                          : b2f(((const unsigned short*)ptrs[a])[i]);
    off += sizes[a];
  }
}

// ------- C = A (MxK) * B^T (NxK), bf16 in, fp32 out, 128x128 tile ---------
__global__ __launch_bounds__(256) void gemm128(
    const unsigned short* __restrict__ A, const unsigned short* __restrict__ B,
    float* __restrict__ C, int M, int N, int K)
{
  __shared__ __align__(16) unsigned short As[128 * 40];
  __shared__ __align__(16) unsigned short Bs[128 * 40];
  const int t = threadIdx.x;
  const int w = t >> 6, lane = t & 63;
  const int quad = lane >> 4, l16 = lane & 15;
  const int wr = w >> 1, wc = w & 1;
  const int m0 = blockIdx.y * 128, n0 = blockIdx.x * 128;
  const int srow = t >> 1;
  const int scol = (t & 1) * 16;

  f4 acc[4][4];
#pragma unroll
  for (int i = 0; i < 4; ++i)
#pragma unroll
    for (int j = 0; j < 4; ++j) acc[i][j] = (f4){0.f, 0.f, 0.f, 0.f};

  const unsigned short* apg = A + (size_t)(m0 + srow) * K + scol;
  const unsigned short* bpg = B + (size_t)(n0 + srow) * K + scol;
  uint4 a0 = *(const uint4*)apg,       a1 = *(const uint4*)(apg + 8);
  uint4 b0 = *(const uint4*)bpg,       b1 = *(const uint4*)(bpg + 8);

  for (int k0 = 0; k0 < K; k0 += 32) {
    __syncthreads();
    *(uint4*)&As[srow * 40 + scol]     = a0;
    *(uint4*)&As[srow * 40 + scol + 8] = a1;
    *(uint4*)&Bs[srow * 40 + scol]     = b0;
    *(uint4*)&Bs[srow * 40 + scol + 8] = b1;
    __syncthreads();
    if (k0 + 32 < K) {
      a0 = *(const uint4*)(apg + k0 + 32); a1 = *(const uint4*)(apg + k0 + 40);
      b0 = *(const uint4*)(bpg + k0 + 32); b1 = *(const uint4*)(bpg + k0 + 40);
    }
    bf16x8 aF[4], bF[4];
#pragma unroll
    for (int i = 0; i < 4; ++i)
      aF[i] = *(const bf16x8*)&As[(wr * 64 + i * 16 + l16) * 40 + quad * 8];
#pragma unroll
    for (int j = 0; j < 4; ++j)
      bF[j] = *(const bf16x8*)&Bs[(wc * 64 + j * 16 + l16) * 40 + quad * 8];
#pragma unroll
    for (int i = 0; i < 4; ++i)
#pragma unroll
      for (int j = 0; j < 4; ++j)
        acc[i][j] = __builtin_amdgcn_mfma_f32_16x16x32_bf16(aF[i], bF[j], acc[i][j], 0, 0, 0);
  }

#pragma unroll
  for (int i = 0; i < 4; ++i)
#pragma unroll
    for (int j = 0; j < 4; ++j)
#pragma unroll
      for (int r = 0; r < 4; ++r) {
        int m = m0 + wr * 64 + i * 16 + quad * 4 + r;
        int n = n0 + wc * 64 + j * 16 + l16;
        C[(size_t)m * N + n] = acc[i][j][r];
      }
}

// ---------------- C = A (MxK) * B^T (NxK), bf16 in, 64x64 tile --------------
template <int MODE>
__global__ __launch_bounds__(256) void gemm_bt(
    const unsigned short* __restrict__ A, const unsigned short* __restrict__ B,
    void* __restrict__ Cv, int M, int N, int K, const int* __restrict__ flag)
{
  __shared__ __align__(16) short As[64 * 40];
  __shared__ __align__(16) short Bs[64 * 40];
  const int t = threadIdx.x;
  const int wave = t >> 6, lane = t & 63;
  const int quad = lane >> 4, l16 = lane & 15;
  const int m0 = blockIdx.y * 64, n0 = blockIdx.x * 64;
  const int srow = t >> 2, scol = (t & 3) * 8;
  f4 acc[4];
#pragma unroll
  for (int i = 0; i < 4; ++i) acc[i] = (f4){0.f, 0.f, 0.f, 0.f};
  const unsigned short* ap = A + (size_t)(m0 + srow) * K + scol;
  const unsigned short* bp = B + (size_t)(n0 + srow) * K + scol;
  for (int k0 = 0; k0 < K; k0 += 32) {
    uint4 av = *(const uint4*)(ap + k0);
    uint4 bv = *(const uint4*)(bp + k0);
    __syncthreads();
    *(uint4*)&As[srow * 40 + scol] = av;
    *(uint4*)&Bs[srow * 40 + scol] = bv;
    __syncthreads();
    bf16x8 af = *(const bf16x8*)&As[(wave * 16 + l16) * 40 + quad * 8];
#pragma unroll
    for (int nt = 0; nt < 4; ++nt) {
      bf16x8 bf = *(const bf16x8*)&Bs[(nt * 16 + l16) * 40 + quad * 8];
      acc[nt] = __builtin_amdgcn_mfma_f32_16x16x32_bf16(af, bf, acc[nt], 0, 0, 0);
    }
  }
  const int outf32 = (MODE == 0) ? 1 : (*flag ? 1 : 0);
#pragma unroll
  for (int nt = 0; nt < 4; ++nt) {
#pragma unroll
    for (int r = 0; r < 4; ++r) {
      int m = m0 + wave * 16 + quad * 4 + r;
      int n = n0 + nt * 16 + l16;
      if (outf32) ((float*)Cv)[(size_t)m * N + n] = acc[nt][r];
      else        ((unsigned short*)Cv)[(size_t)m * N + n] = f2b(acc[nt][r]);
    }
  }
}

// ------- fused conv + cumsum:
//   blocks <4096:      Q/K conv elementwise -> qc [L][2048]
//   blocks 4096..4607: V conv + inline-dt scale + LDS transpose -> vt
//   blocks 4608..4623: per-head A cumsum -> Acum (dt recomputed inline)
__global__ __launch_bounds__(256) void conv_kernel(
    const float* __restrict__ qkvf, const float* __restrict__ smallf,
    unsigned short* __restrict__ qc, unsigned short* __restrict__ vt,
    float* __restrict__ Ac)
{
  if (blockIdx.x < 4096) {
    const int idx = blockIdx.x * 256 + threadIdx.x;
    const int l = idx >> 9;                 // / 512
    const int c = (idx & 511) * 4;          // 0..2044
    f4 xc = *(const f4*)&qkvf[(size_t)l * QKV_P + c];
    f4 xp = (f4){0.f, 0.f, 0.f, 0.f};
    if (l > 0) xp = *(const f4*)&qkvf[(size_t)(l - 1) * QKV_P + c];
    const float* w; const float* b; int cb;
    if (c < HIDN) { w = smallf;        b = smallf + 2048; cb = c; }
    else          { w = smallf + 3072; b = smallf + 5120; cb = c - HIDN; }
    f4 o;
#pragma unroll
    for (int j = 0; j < 4; ++j)
      o[j] = b[cb + j] + xp[j] * w[(cb + j) * 2] + xc[j] * w[(cb + j) * 2 + 1];
    ushort4 st;
    st.x = f2h(o[0]); st.y = f2h(o[1]); st.z = f2h(o[2]); st.w = f2h(o[3]);
    *(ushort4*)&qc[(size_t)l * QC_S + c] = st;
  } else if (blockIdx.x < 4608) {
    __shared__ __align__(16) unsigned short Ts[64 * 68];
    const int bv = blockIdx.x - 4096;       // 0..511
    const int h = bv & 15;
    const int lt0 = bv >> 4;                // 0..31
    const int t = threadIdx.x;
    const int srow = t >> 2, cc = t & 3;
    const int l = lt0 * 64 + srow;
    const int cb = h * 64 + cc * 16;        // V-channel base (0..1023)
    const float* w = smallf + 6144;
    const float* b = smallf + 8192;
    // inline dt = softplus(qkvf[l][3072+h] + dt_proj_b + dt_bias)
    const float z = qkvf[(size_t)l * QKV_P + 3072 + h]
                  + smallf[9312 + h] + smallf[9296 + h];
    const float dtv = (z > 20.f) ? z : log1pf(expf(z));
    const float* xcp = &qkvf[(size_t)l * QKV_P + 2048 + cb];
    const float* xpp = &qkvf[(size_t)(l - 1) * QKV_P + 2048 + cb];
    unsigned short o16[16];
#pragma unroll
    for (int g = 0; g < 4; ++g) {
      f4 xc = *(const f4*)(xcp + g * 4);
      f4 xp = (f4){0.f, 0.f, 0.f, 0.f};
      if (l > 0) xp = *(const f4*)(xpp + g * 4);
#pragma unroll
      for (int j = 0; j < 4; ++j) {
        const int ch = cb + g * 4 + j;
        float o = b[ch] + xp[j] * w[ch * 2] + xc[j] * w[ch * 2 + 1];
        o16[g * 4 + j] = f2h(o * dtv);
      }
    }
    *(uint4*)&Ts[srow * 68 + cc * 16]     = *(const uint4*)&o16[0];
    *(uint4*)&Ts[srow * 68 + cc * 16 + 8] = *(const uint4*)&o16[8];
    __syncthreads();
    __align__(16) unsigned short o[16];
#pragma unroll
    for (int j = 0; j < 16; ++j) o[j] = Ts[(cc * 16 + j) * 68 + srow];
    unsigned short* op = vt + ((size_t)h * DHD + srow) * L_SEQ + lt0 * 64 + cc * 16;
    *(uint4*)op = *(const uint4*)&o[0];
    *(uint4*)(op + 8) = *(const uint4*)&o[8];
  } else {
    const int h = blockIdx.x - 4608;
    const int lane = threadIdx.x;
    if (lane < 64) {
      const int base = lane * 32;
      const float dpb = smallf[9312 + h], dtb = smallf[9296 + h];
      const float nal = -expf(smallf[9280 + h]);
      float Av[32];
      float run = 0.f;
#pragma unroll
      for (int i = 0; i < 32; ++i) {
        const int l = base + i;
        float z = qkvf[(size_t)l * QKV_P + 3072 + h] + dpb + dtb;
        float dtv = (z > 20.f) ? z : log1pf(expf(z));
        Av[i] = nal * dtv;
        run += Av[i];
      }
      float incl = run;
#pragma unroll
      for (int off = 1; off < 64; off <<= 1) {
        float n = __shfl_up(incl, off);
        if (lane >= off) incl += n;
      }
      float r2 = incl - run;
#pragma unroll
      for (int i = 0; i < 32; ++i) {
        r2 += Av[i];
        Ac[h * L_SEQ + base + i] = r2;
      }
    }
  }
}

// ------- gated causal attention, split-m halves, fp32 partials -------------
// grid 1024: n -> r=n&7 (XCD under RR%8), hh=(n>>3)&1, k=n>>4 in [0,64):
//   h = r+8*hh; lt = 31-(k>>1) (BIGGEST halves dispatch first: LPT greedy);
//   s = k&1 selects m-half [0,ceil(nT/2)) or [ceil(nT/2),nT), nT=lt+1.
// Gate sum over m is linear (no softmax renorm) -> halves add exactly;
// reduce_kernel sums po0+po1 + RMSNorm. Verified split machinery (R10) +
// verified LDS loop (R11). LDS 46080B -> 3 blocks/CU.
__global__ __launch_bounds__(256) void attn_kernel(
    const unsigned short* __restrict__ qc,     // fp16 [L][2048] (Q,K)
    const unsigned short* __restrict__ vt,     // fp16 [NH][DHD][L] (V^T)
    const float* __restrict__ Ac,              // [NH][L]
    const float* __restrict__ smallf,
    float* __restrict__ po)                    // fp32 [2][L][1024] partials
{
  const int n  = blockIdx.x;
  const int r_ = n & 7;
  const int hh = (n >> 3) & 1;
  const int k_ = n >> 4;                   // 0..63
  const int h  = r_ + 8 * hh;
  const int lt = 31 - (k_ >> 1);
  const int s_ = k_ & 1;
  const int nT = lt + 1;
  const int mS = s_ ? ((nT + 1) >> 1) : 0;
  const int mE = s_ ? nT : ((nT + 1) >> 1);

  const int t  = threadIdx.x;
  const int w    = t >> 6;
  const int lane = t & 63;
  const int l16  = lane & 15;
  const int quad = lane >> 4;
  const int srow = t >> 2;
  const int cc   = t & 3;

  __shared__ __align__(16) unsigned short K_lds[2][64 * LP];  // K[m][d]
  __shared__ __align__(16) unsigned short V_lds[2][64 * LP];  // V^T[d][m]
  __shared__ __align__(16) unsigned short S_lds[64 * LP];     // S[l][m]

  const int l0 = lt * 64;
  const float rc = 1.0f / smallf[9328 + h];
  const float* Acp = Ac + h * L_SEQ;

  H8 qf0, qf1;
  {
    const unsigned short* qp =
        qc + (size_t)(l0 + w * 16 + l16) * QC_S + h * DHD + quad * 8;
    qf0.u4 = *(const uint4*)qp;
    qf1.u4 = *(const uint4*)(qp + 32);
  }
  float alv[4];
#pragma unroll
  for (int r = 0; r < 4; ++r) alv[r] = Acp[l0 + w * 16 + quad * 4 + r];

  f4 acc[4];
#pragma unroll
  for (int i = 0; i < 4; ++i) acc[i] = (f4){0.f, 0.f, 0.f, 0.f};

  const unsigned short* kgp =
      qc + (size_t)srow * QC_S + HIDN + h * DHD + cc * 16;
  const unsigned short* vgp =
      vt + ((size_t)h * DHD + srow) * L_SEQ + cc * 16;
  const int swo = srow * LP + cc * 16;

  if (mS < mE) {                           // block-uniform guard
    uint4 k0v = *(const uint4*)(kgp + (size_t)mS * 64 * QC_S);
    uint4 k1v = *(const uint4*)(kgp + (size_t)mS * 64 * QC_S + 8);
    uint4 v0v = *(const uint4*)(vgp + (size_t)mS * 64);
    uint4 v1v = *(const uint4*)(vgp + (size_t)mS * 64 + 8);
    float amv[4];
#pragma unroll
    for (int nt = 0; nt < 4; ++nt) amv[nt] = Acp[mS * 64 + nt * 16 + l16];

    *(uint4*)&K_lds[0][swo]     = k0v;
    *(uint4*)&K_lds[0][swo + 8] = k1v;
    *(uint4*)&V_lds[0][swo]     = v0v;
    *(uint4*)&V_lds[0][swo + 8] = v1v;
    __syncthreads();

    int cur = 0;
    for (int it = mS; it < mE; ++it) {
      uint4 nk0 = k0v, nk1 = k1v, nv0 = v0v, nv1 = v1v;
      float namv[4];
      const bool more = (it + 1 < mE);
      if (more) {
        const unsigned short* kp = kgp + (size_t)(it + 1) * 64 * QC_S;
        const unsigned short* vp = vgp + (size_t)(it + 1) * 64;
        nk0 = *(const uint4*)kp; nk1 = *(const uint4*)(kp + 8);
        nv0 = *(const uint4*)vp; nv1 = *(const uint4*)(vp + 8);
#pragma unroll
        for (int nt = 0; nt < 4; ++nt)
          namv[nt] = Acp[(it + 1) * 64 + nt * 16 + l16];
      }

      // ---- QK^T (b128 fragment reads) ----
      f4 s[4];
#pragma unroll
      for (int i = 0; i < 4; ++i) s[i] = (f4){0.f, 0.f, 0.f, 0.f};
#pragma unroll
      for (int ks = 0; ks < 2; ++ks) {
        H8 qk = ks ? qf1 : qf0;
#pragma unroll
        for (int nt = 0; nt < 4; ++nt) {
          H8 kf;
          kf.u4 = *(const uint4*)&K_lds[cur][(nt * 16 + l16) * LP + ks * 32 + quad * 8];
          s[nt] = __builtin_amdgcn_mfma_f32_16x16x32_f16(qk.h, kf.h, s[nt], 0, 0, 0);
        }
      }
      // ---- gate + S write (causal compare only on diagonal tile) ----
      const int m0 = it * 64;
      if (it == lt) {
#pragma unroll
        for (int nt = 0; nt < 4; ++nt) {
          const int mg = m0 + nt * 16 + l16;
          const float am = amv[nt];
#pragma unroll
          for (int r = 0; r < 4; ++r) {
            const int lg = l0 + w * 16 + quad * 4 + r;
            float val = (mg <= lg) ? s[nt][r] * __expf(alv[r] - am) * rc : 0.0f;
            S_lds[(w * 16 + quad * 4 + r) * LP + nt * 16 + l16] = f2h(val);
          }
        }
      } else {
#pragma unroll
        for (int nt = 0; nt < 4; ++nt) {
          const float am = amv[nt];
#pragma unroll
          for (int r = 0; r < 4; ++r) {
            float val = s[nt][r] * __expf(alv[r] - am) * rc;
            S_lds[(w * 16 + quad * 4 + r) * LP + nt * 16 + l16] = f2h(val);
          }
        }
      }
      // ---- PV (wave-private S rows; b128 reads) ----
#pragma unroll
      for (int ks = 0; ks < 2; ++ks) {
        H8 sa;
        sa.u4 = *(const uint4*)&S_lds[(w * 16 + l16) * LP + ks * 32 + quad * 8];
#pragma unroll
        for (int db = 0; db < 4; ++db) {
          H8 vb;
          vb.u4 = *(const uint4*)&V_lds[cur][(db * 16 + l16) * LP + ks * 32 + quad * 8];
          acc[db] = __builtin_amdgcn_mfma_f32_16x16x32_f16(sa.h, vb.h, acc[db], 0, 0, 0);
        }
      }
      // ---- stage next tile (b128) + one barrier ----
      if (more) {
        unsigned short* Kl = K_lds[cur ^ 1];
        unsigned short* Vl = V_lds[cur ^ 1];
        *(uint4*)&Kl[swo]     = nk0;
        *(uint4*)&Kl[swo + 8] = nk1;
        *(uint4*)&Vl[swo]     = nv0;
        *(uint4*)&Vl[swo + 8] = nv1;
#pragma unroll
        for (int nt = 0; nt < 4; ++nt) amv[nt] = namv[nt];
        __syncthreads();
        cur ^= 1;
      }
    }
  }

  // ---- write fp32 partials (zeros if this half had no work) ----
  float* pout = po + (size_t)s_ * (L_SEQ * HIDN);
#pragma unroll
  for (int r = 0; r < 4; ++r) {
    float* op = pout + (size_t)(l0 + w * 16 + quad * 4 + r) * HIDN + h * DHD + l16;
#pragma unroll
    for (int db = 0; db < 4; ++db)
      op[db * 16] = acc[db][r];
  }
}

// ------- reduce: po0+po1, RMSNorm over d=64, bf16 store --------------------
__global__ __launch_bounds__(256) void reduce_kernel(
    const float* __restrict__ po, const float* __restrict__ smallf,
    unsigned short* __restrict__ attn_out)
{
  const int l = blockIdx.x;
  const int t = threadIdx.x;
  const int col = t * 4;
  const float* p0 = po + (size_t)l * HIDN + col;
  const float* p1 = p0 + (size_t)L_SEQ * HIDN;
  f4 a = *(const f4*)p0;
  f4 b = *(const f4*)p1;
  f4 o = a + b;
  float p = o[0] * o[0] + o[1] * o[1] + o[2] * o[2] + o[3] * o[3];
#pragma unroll
  for (int off = 1; off < 16; off <<= 1) p += __shfl_xor(p, off);
  const float rn = rsqrtf(p * (1.0f / 64.0f) + 1.1920928955078125e-07f);
  const int d0 = col & 63;
  ushort4 st;
  st.x = f2b(o[0] * rn * smallf[9216 + d0]);
  st.y = f2b(o[1] * rn * smallf[9216 + d0 + 1]);
  st.z = f2b(o[2] * rn * smallf[9216 + d0 + 2]);
  st.w = f2b(o[3] * rn * smallf[9216 + d0 + 3]);
  *(ushort4*)&attn_out[(size_t)l * HIDN + col] = st;
}

extern "C" void kernel_launch(void* const* d_in, const int* in_sizes, int n_in,
                              void* d_out, int out_size, void* d_ws, size_t ws_size,
                              hipStream_t stream)
{
  (void)in_sizes; (void)n_in; (void)out_size; (void)ws_size;
  const void* hs        = d_in[0];
  // d_in[1] = attention_mask: deterministic causal triu — handled analytically
  const void* qkv_w     = d_in[2];
  const void* q_conv_w  = d_in[3];
  const void* q_conv_b  = d_in[4];
  const void* k_conv_w  = d_in[5];
  const void* k_conv_b  = d_in[6];
  const void* v_conv_w  = d_in[7];
  const void* v_conv_b  = d_in[8];
  const void* norm_w    = d_in[9];
  const void* A_log     = d_in[10];
  const void* dt_bias   = d_in[11];
  const void* dt_proj_w = d_in[12];
  const void* dt_proj_b = d_in[13];
  const void* o_w       = d_in[14];
  const void* ordc      = d_in[15];

  char* ws = (char*)d_ws;
  int* flag             = (int*)ws;                              // @0
  unsigned short* hs_b  = (unsigned short*)(ws + 256);           // 4,194,304
  unsigned short* qkvw_b= (unsigned short*)(ws + 4194560);       // 6,553,600 ([3200][1024])
  unsigned short* ow_b  = (unsigned short*)(ws + 10748160);      // 2,097,152
  float* smallf         = (float*)(ws + 12845312);               // 37,376
  float* qkvf           = (float*)(ws + 12882688);               // 26,214,400 ([2048][3200] f32)
  unsigned short* qc_h  = (unsigned short*)(ws + 39097088);      // 8,388,608 ([2048][2048] f16)
  float* Acum           = (float*)(ws + 47616768);               // 131,072
  unsigned short* attnb = (unsigned short*)(ws + 47747840);      // 4,194,304
  unsigned short* vt_h  = (unsigned short*)(ws + 51942144);      // 4,194,304
  float* po             = (float*)(ws + 56136448);               // 16,777,216 ([2][2048][1024] f32)

  prep_kernel<<<1024, 256, 0, stream>>>(
      hs, qkv_w, o_w, dt_proj_w,
      q_conv_w, q_conv_b, k_conv_w, k_conv_b, v_conv_w, v_conv_b,
      norm_w, A_log, dt_bias, dt_proj_b, ordc,
      hs_b, qkvw_b, ow_b, smallf, flag);

  gemm128<<<dim3(QKV_P / 128, L_SEQ / 128), 256, 0, stream>>>(
      hs_b, qkvw_b, qkvf, L_SEQ, QKV_P, HIDN);
  conv_kernel<<<4096 + 512 + 16, 256, 0, stream>>>(qkvf, smallf, qc_h, vt_h, Acum);
  attn_kernel<<<1024, 256, 0, stream>>>(qc_h, vt_h, Acum, smallf, po);
  reduce_kernel<<<L_SEQ, 256, 0, stream>>>(po, smallf, attnb);
  gemm_bt<1><<<dim3(HIDN / 64, L_SEQ / 64), 256, 0, stream>>>(
      attnb, ow_b, d_out, L_SEQ, HIDN, HIDN, flag);
}